// Round 9
// baseline (485.983 us; speedup 1.0000x reference)
//
#include <hip/hip_runtime.h>

#define NN 50000
#define NE 600000
#define DIM 128
#define NB_N 196   // ceil(50000/256)
#define NB_E 2344  // ceil(600000/256)
#define TILES 3125 // 50000/16
#define NEPAD (NE + 8 * NN + 64)  // rows padded to multiple of 8, min 8
#define SLOTN 25000   // dst nodes per slot-half
#define SLOTBLKS 782  // ceil(25000/32) blocks per slot
#define AGG_GRID (8 * SLOTBLKS)

typedef unsigned short u16;
typedef unsigned int u32;
typedef __attribute__((ext_vector_type(8))) short bf16x8;
typedef __attribute__((ext_vector_type(4))) float f32x4;

__device__ __forceinline__ u16 f2bf(float f) {
    u32 u = __builtin_bit_cast(u32, f);
    u32 r = (u + 0x7FFFu + ((u >> 16) & 1u)) >> 16;
    return (u16)r;
}
__device__ __forceinline__ float bflo(u32 w) { return __builtin_bit_cast(float, w << 16); }
__device__ __forceinline__ float bfhi(u32 w) { return __builtin_bit_cast(float, w & 0xffff0000u); }
__device__ __forceinline__ int pad8(int d) {
    int p = (d + 7) & ~7;
    return p < 8 ? 8 : p;
}

// ---- CSR build -------------------------------------------------------------

__global__ __launch_bounds__(256) void k_count(const int* __restrict__ ei,
                                               int* __restrict__ deg) {
    __shared__ int s64;
    if (threadIdx.x == 0) {
        int o = 0;
#pragma unroll
        for (int j = 0; j < 16; j++) o |= ei[2 * j + 1];  // int64 => high words 0
        s64 = (o == 0);
    }
    __syncthreads();
    int e = blockIdx.x * 256 + threadIdx.x;
    if (e >= NE) return;
    int d = s64 ? ei[2 * (NE + e)] : ei[NE + e];
    atomicAdd(&deg[d], 1);
}

// exclusive scan of pad8(deg) -> rp8 (two-level, multi-block)
__global__ __launch_bounds__(256) void k_scanA(const int* __restrict__ deg,
                                               int* __restrict__ rp8,
                                               int* __restrict__ bsum) {
    __shared__ int buf[256];
    int t = threadIdx.x, i = blockIdx.x * 256 + t;
    int v = (i < NN) ? pad8(deg[i]) : 0;
    buf[t] = v;
    __syncthreads();
    for (int off = 1; off < 256; off <<= 1) {
        int x = (t >= off) ? buf[t - off] : 0;
        __syncthreads();
        buf[t] += x;
        __syncthreads();
    }
    if (i < NN) rp8[i] = buf[t] - v;
    if (t == 255) bsum[blockIdx.x] = buf[255];
}

__global__ __launch_bounds__(256) void k_scanB(int* __restrict__ bsum) {
    __shared__ int buf[256];
    int t = threadIdx.x;
    int v = (t < NB_N) ? bsum[t] : 0;
    buf[t] = v;
    __syncthreads();
    for (int off = 1; off < 256; off <<= 1) {
        int x = (t >= off) ? buf[t - off] : 0;
        __syncthreads();
        buf[t] += x;
        __syncthreads();
    }
    bsum[t] = buf[t] - v;
}

__global__ __launch_bounds__(256) void k_scanC(const int* __restrict__ deg,
                                               int* __restrict__ rp8,
                                               const int* __restrict__ bsum,
                                               float* __restrict__ dinv) {
    int i = blockIdx.x * 256 + threadIdx.x;
    if (i < NN) {
        rp8[i] += bsum[i >> 8];
        dinv[i] = rsqrtf((float)(deg[i] + 1));  // +1 self loop
    }
    if (i == 0) rp8[NN] = bsum[255];
}

// fill CSR (src only, 4 B) + secondary work: wcast, pad entries -> NN, zero
// sentinel row of hwA
__global__ __launch_bounds__(256) void k_fill(const int* __restrict__ ei,
                                              const int* __restrict__ rp8,
                                              int* __restrict__ cursor,
                                              const int* __restrict__ deg,
                                              int* __restrict__ recs,
                                              const float* __restrict__ W0,
                                              const float* __restrict__ W1,
                                              const float* __restrict__ W2,
                                              u16* __restrict__ Wt,
                                              u16* __restrict__ hwA) {
    __shared__ int s64;
    if (threadIdx.x == 0) {
        int o = 0;
#pragma unroll
        for (int j = 0; j < 16; j++) o |= ei[2 * j + 1];
        s64 = (o == 0);
    }
    __syncthreads();
    int e = blockIdx.x * 256 + threadIdx.x;
    if (e < NE) {
        int is64 = s64;
        int s = is64 ? ei[2 * e] : ei[e];
        int d = is64 ? ei[2 * (NE + e)] : ei[NE + e];
        int pos = rp8[d] + atomicAdd(&cursor[d], 1);
        recs[pos] = s;
    }
    // secondary roles
    int b = blockIdx.x;
    if (b < 192) {  // weight cast: Wt[layer][n][k] = bf16(W[layer][k][n])
        int idx = b * 256 + threadIdx.x;  // < 49152 = 3*16384
        int l = idx >> 14, rem = idx & 16383;
        int n = rem >> 7, k = rem & 127;
        const float* W = (l == 0) ? W0 : ((l == 1) ? W1 : W2);
        Wt[idx] = f2bf(W[k * 128 + n]);
    } else if (b < 388) {  // pad entries -> sentinel row NN
        int i = (b - 192) * 256 + threadIdx.x;
        if (i < NN) {
            int rp = rp8[i], d = deg[i], p = pad8(d);
            for (int j = d; j < p; j++) recs[rp + j] = NN;
        }
    } else if (b == 388) {  // zero sentinel row of hwA (256 B)
        if (threadIdx.x < 64)
            ((u32*)(hwA + (size_t)NN * DIM))[threadIdx.x] = 0;
    }
}

// ---- layer-1 GEMM: hw'[v] = dinv[v] * (bf16(x) @ W0) -----------------------
__global__ __launch_bounds__(256) void k_gemm_f32(const float* __restrict__ x,
                                                  const u16* __restrict__ Wt,
                                                  const float* __restrict__ dinv,
                                                  u16* __restrict__ hwb) {
    int lane = threadIdx.x & 63;
    int tile = blockIdx.x * 4 + (threadIdx.x >> 6);
    if (tile >= TILES) return;
    int r = lane & 15, q = lane >> 4;

    bf16x8 Bf[8][4];
#pragma unroll
    for (int nt = 0; nt < 8; nt++)
#pragma unroll
        for (int kc = 0; kc < 4; kc++)
            Bf[nt][kc] = *(const bf16x8*)(Wt + ((nt * 16 + r) << 7) + kc * 32 + q * 8);

    long rowbase = (long)tile * 16;
    bf16x8 Af[4];
#pragma unroll
    for (int kc = 0; kc < 4; kc++) {
        const float4* p = (const float4*)(x + (rowbase + r) * 128 + kc * 32 + q * 8);
        float4 t0 = p[0], t1 = p[1];
        bf16x8 a;
        a[0] = (short)f2bf(t0.x); a[1] = (short)f2bf(t0.y);
        a[2] = (short)f2bf(t0.z); a[3] = (short)f2bf(t0.w);
        a[4] = (short)f2bf(t1.x); a[5] = (short)f2bf(t1.y);
        a[6] = (short)f2bf(t1.z); a[7] = (short)f2bf(t1.w);
        Af[kc] = a;
    }

    float dv[4];
#pragma unroll
    for (int i = 0; i < 4; i++) dv[i] = dinv[rowbase + q * 4 + i];

#pragma unroll
    for (int nt = 0; nt < 8; nt++) {
        f32x4 acc = {0.f, 0.f, 0.f, 0.f};
#pragma unroll
        for (int kc = 0; kc < 4; kc++)
            acc = __builtin_amdgcn_mfma_f32_16x16x32_bf16(Af[kc], Bf[nt][kc], acc, 0, 0, 0);
#pragma unroll
        for (int i = 0; i < 4; i++)
            hwb[(rowbase + q * 4 + i) * 128 + nt * 16 + r] = f2bf(dv[i] * acc[i]);
    }
}

// ---- GEMM (bf16 in): hw'[v] = dinv[v] * (h @ W) ----------------------------
__global__ __launch_bounds__(256) void k_gemm(const u16* __restrict__ hb,
                                              const u16* __restrict__ Wt,
                                              const float* __restrict__ dinv,
                                              u16* __restrict__ hwb) {
    int lane = threadIdx.x & 63;
    int tile = blockIdx.x * 4 + (threadIdx.x >> 6);
    if (tile >= TILES) return;
    int r = lane & 15, q = lane >> 4;

    bf16x8 Bf[8][4];
#pragma unroll
    for (int nt = 0; nt < 8; nt++)
#pragma unroll
        for (int kc = 0; kc < 4; kc++)
            Bf[nt][kc] = *(const bf16x8*)(Wt + ((nt * 16 + r) << 7) + kc * 32 + q * 8);

    long rowbase = (long)tile * 16;
    bf16x8 Af[4];
#pragma unroll
    for (int kc = 0; kc < 4; kc++)
        Af[kc] = *(const bf16x8*)(hb + ((rowbase + r) << 7) + kc * 32 + q * 8);

    float dv[4];
#pragma unroll
    for (int i = 0; i < 4; i++) dv[i] = dinv[rowbase + q * 4 + i];

#pragma unroll
    for (int nt = 0; nt < 8; nt++) {
        f32x4 acc = {0.f, 0.f, 0.f, 0.f};
#pragma unroll
        for (int kc = 0; kc < 4; kc++)
            acc = __builtin_amdgcn_mfma_f32_16x16x32_bf16(Af[kc], Bf[nt][kc], acc, 0, 0, 0);
#pragma unroll
        for (int i = 0; i < 4; i++)
            hwb[(rowbase + q * 4 + i) * 128 + nt * 16 + r] = f2bf(dv[i] * acc[i]);
    }
}

// ---- XCD-affine sliced aggregation -----------------------------------------
// slot = blockIdx & 7 (round-robin -> XCD heuristic). pass = slot>>1 owns
// feature slice [32*pass, 32*pass+32) = 64 B = ONE cache line of every row ->
// per-XCD gather slab = 3.2 MB, fits 4 MiB L2. half = slot&1 owns 25K dst
// nodes. Wave: fq = lane&7 (4 feats, 8 B), sl = lane>>3 (edge slot, 8/iter);
// rows padded to mult-8 with sentinel-NN entries -> branchless loop.
__global__ __launch_bounds__(256) void k_agg_s(const u16* __restrict__ hw_in,
                                               const int* __restrict__ rp8,
                                               const int* __restrict__ recs,
                                               const float* __restrict__ dinv,
                                               const float* __restrict__ bias,
                                               u16* __restrict__ bf_out,
                                               float* __restrict__ f_out,
                                               int write_f32) {
    int b = blockIdx.x;
    int slot = b & 7, j = b >> 3;
    int pass = slot >> 1, half = slot & 1;
    int lane = threadIdx.x & 63;
    int w = threadIdx.x >> 6;
    int fq = lane & 7, sl = lane >> 3;
    int fbase = pass * 32 + fq * 4;  // u16 offset within row
    int vloc0 = j * 32 + w * 8;
#pragma unroll 1
    for (int i = 0; i < 8; i++) {
        int vloc = vloc0 + i;
        if (vloc >= SLOTN) return;
        int v = half * SLOTN + vloc;
        int start = rp8[v], end = rp8[v + 1];
        uint2 sv = *(const uint2*)(hw_in + (size_t)v * DIM + fbase);
        float m = (sl == 0) ? 1.0f : 0.0f;  // self term counted once
        float a0 = m * bflo(sv.x), a1 = m * bfhi(sv.x);
        float a2 = m * bflo(sv.y), a3 = m * bfhi(sv.y);
        for (int e0 = start; e0 < end; e0 += 8) {
            int src = __builtin_nontemporal_load(recs + e0 + sl);
            uint2 u = *(const uint2*)(hw_in + (size_t)(u32)src * DIM + fbase);
            a0 += bflo(u.x); a1 += bfhi(u.x);
            a2 += bflo(u.y); a3 += bfhi(u.y);
        }
        // reduce over edge slots (lane bits 3..5)
        a0 += __shfl_xor(a0, 8, 64);  a1 += __shfl_xor(a1, 8, 64);
        a2 += __shfl_xor(a2, 8, 64);  a3 += __shfl_xor(a3, 8, 64);
        a0 += __shfl_xor(a0, 16, 64); a1 += __shfl_xor(a1, 16, 64);
        a2 += __shfl_xor(a2, 16, 64); a3 += __shfl_xor(a3, 16, 64);
        a0 += __shfl_xor(a0, 32, 64); a1 += __shfl_xor(a1, 32, 64);
        a2 += __shfl_xor(a2, 32, 64); a3 += __shfl_xor(a3, 32, 64);
        if (sl == 0) {
            float dv = dinv[v];
            float4 bb = *(const float4*)(bias + fbase);
            float r0 = fmaxf(fmaf(dv, a0, bb.x), 0.f);
            float r1 = fmaxf(fmaf(dv, a1, bb.y), 0.f);
            float r2 = fmaxf(fmaf(dv, a2, bb.z), 0.f);
            float r3 = fmaxf(fmaf(dv, a3, bb.w), 0.f);
            if (write_f32) {
                *(float4*)(f_out + (size_t)v * DIM + fbase) =
                    make_float4(r0, r1, r2, r3);
            } else {
                uint2 pk;
                pk.x = (u32)f2bf(r0) | ((u32)f2bf(r1) << 16);
                pk.y = (u32)f2bf(r2) | ((u32)f2bf(r3) << 16);
                *(uint2*)(bf_out + (size_t)v * DIM + fbase) = pk;
            }
        }
    }
}

// ---- launch ----------------------------------------------------------------

extern "C" void kernel_launch(void* const* d_in, const int* in_sizes, int n_in,
                              void* d_out, int out_size, void* d_ws, size_t ws_size,
                              hipStream_t stream) {
    const float* x = (const float*)d_in[0];
    const int* ei = (const int*)d_in[1];
    const float* W0 = (const float*)d_in[2];
    const float* b0 = (const float*)d_in[3];
    const float* W1 = (const float*)d_in[4];
    const float* b1 = (const float*)d_in[5];
    const float* W2 = (const float*)d_in[6];
    const float* b2 = (const float*)d_in[7];

    char* ws = (char*)d_ws;
    size_t off = 0;
    auto alloc = [&](size_t bytes) -> void* {
        void* p = ws + off;
        off += (bytes + 511) & ~(size_t)511;
        return p;
    };
    int* deg = (int*)alloc(NN * 4);      // zeroed
    int* cursor = (int*)alloc(NN * 4);   // zeroed
    size_t zbytes = off;
    int* recs = (int*)alloc((size_t)NEPAD * 4);
    float* dinv = (float*)alloc(NN * 4);
    int* rp8 = (int*)alloc((NN + 1) * 4);
    int* bsum = (int*)alloc(256 * 4);
    u16* Wt = (u16*)alloc(3 * 128 * 128 * 2);
    u16* hwA = (u16*)alloc((size_t)(NN + 1) * DIM * 2);  // +1 sentinel row
    u16* hB = (u16*)alloc((size_t)NN * DIM * 2);

    hipMemsetAsync(ws, 0, zbytes, stream);
    k_count<<<NB_E, 256, 0, stream>>>(ei, deg);
    k_scanA<<<NB_N, 256, 0, stream>>>(deg, rp8, bsum);
    k_scanB<<<1, 256, 0, stream>>>(bsum);
    k_scanC<<<NB_N, 256, 0, stream>>>(deg, rp8, bsum, dinv);
    k_fill<<<NB_E, 256, 0, stream>>>(ei, rp8, cursor, deg, recs,
                                     W0, W1, W2, Wt, hwA);
    k_gemm_f32<<<(TILES + 3) / 4, 256, 0, stream>>>(x, Wt, dinv, hwA);
    k_agg_s<<<AGG_GRID, 256, 0, stream>>>(hwA, rp8, recs, dinv, b0,
                                          hB, nullptr, 0);
    k_gemm<<<(TILES + 3) / 4, 256, 0, stream>>>(hB, Wt + 16384, dinv, hwA);
    k_agg_s<<<AGG_GRID, 256, 0, stream>>>(hwA, rp8, recs, dinv, b1,
                                          hB, nullptr, 0);
    k_gemm<<<(TILES + 3) / 4, 256, 0, stream>>>(hB, Wt + 32768, dinv, hwA);
    k_agg_s<<<AGG_GRID, 256, 0, stream>>>(hwA, rp8, recs, dinv, b2,
                                          nullptr, (float*)d_out, 1);
}